// Round 2
// baseline (230.428 us; speedup 1.0000x reference)
//
#include <hip/hip_runtime.h>

// Problem constants (T=8 tables, L=2e6 indices/table, B=16384 batch)
// Outputs (flat f32, concatenated): [0] combined_indices 16M, [1] combined_offsets 131073,
// [2] combined_weights 16M. d_out is read back as float32 by the harness.
constexpr long NA = 16000000;   // T*L
constexpr long NB = 131073;     // T*B+1
constexpr int  BLK = 256;
constexpr int  GA = (2000000 + BLK - 1) / BLK;   // 7813 blocks, 8 elems/thread (indices)
constexpr int  GC = (2000000 + BLK - 1) / BLK;   // 7813 blocks, 8 elems/thread (weights)
constexpr int  GB = ((int)NB + BLK - 1) / BLK;   // 513 blocks, scalar (offsets)

__global__ __launch_bounds__(BLK) void tbe_prep(
    const int* __restrict__ indices,
    const int* __restrict__ offsets,
    const float* __restrict__ weights,
    float* __restrict__ out) {
  const int bid = blockIdx.x;
  const int tid = threadIdx.x;

  if (bid < GA) {
    // ---- Output 0: combined_indices = indices.reshape(-1), int32 -> f32 (exact) ----
    long i = (long)bid * BLK + tid;            // chunk id, 8 elements each
    if (i < 2000000) {
      const int4* p = (const int4*)indices;
      int4 a = p[2 * i];
      int4 b = p[2 * i + 1];
      float4 ra = make_float4((float)a.x, (float)a.y, (float)a.z, (float)a.w);
      float4 rb = make_float4((float)b.x, (float)b.y, (float)b.z, (float)b.w);
      float4* o = (float4*)out;                // region starts at byte 0, 16-aligned
      o[2 * i]     = ra;
      o[2 * i + 1] = rb;
    }
  } else if (bid < GA + GC) {
    // ---- Output 2: combined_weights = per_sample_weights.reshape(-1), f32 copy ----
    long c = (long)(bid - GA) * BLK + tid;     // chunk id, 8 elements each
    if (c < 2000000) {
      const float4* p = (const float4*)weights;
      float4 a = p[2 * c];
      float4 b = p[2 * c + 1];
      // Region starts at element NA+NB = 16,131,073 -> byte 64,524,292 == 4 (mod 16).
      // Split each 8-elem (32 B) chunk into naturally-aligned 1+2+4+1 stores.
      float* base = out + (NA + NB) + 8 * c;
      base[0] = a.x;                                   // byte%4==0
      float2 s1; s1.x = a.y; s1.y = a.z;
      *(float2*)(base + 1) = s1;                       // byte%8==0
      float4 s2; s2.x = a.w; s2.y = b.x; s2.z = b.y; s2.w = b.z;
      *(float4*)(base + 3) = s2;                       // byte%16==0
      base[7] = b.w;                                   // byte%4==0
    }
  } else {
    // ---- Output 1: combined_offsets, scalar (131,073 elements) ----
    long j = (long)(bid - GA - GC) * BLK + tid;
    if (j < NB) {
      int v;
      if (j == NB - 1) {
        v = 16000000;                           // T*L sentinel
      } else {
        int t = (int)(j >> 14);                 // j / B, B=16384
        int k = (int)(j & 16383);               // j % B
        v = offsets[t * 16385 + k] + t * 2000000;  // offsets[t, :B] + t*L
      }
      out[NA + j] = (float)v;
    }
  }
}

extern "C" void kernel_launch(void* const* d_in, const int* in_sizes, int n_in,
                              void* d_out, int out_size, void* d_ws, size_t ws_size,
                              hipStream_t stream) {
  const int*   indices = (const int*)d_in[0];
  const int*   offsets = (const int*)d_in[1];
  const float* weights = (const float*)d_in[2];
  float*       out     = (float*)d_out;

  const int grid = GA + GC + GB;  // 16,139 blocks
  tbe_prep<<<dim3(grid), dim3(BLK), 0, stream>>>(indices, offsets, weights, out);
}

// Round 5
// 220.810 us; speedup vs baseline: 1.0436x; 1.0436x over previous
//
#include <hip/hip_runtime.h>

// T=8, L=2e6, B=16384. Outputs (flat f32 concat): [0] indices 16M, [1] offsets 131073, [2] weights 16M.
constexpr long NA = 16000000;   // T*L
constexpr long NB = 131073;     // T*B+1
constexpr int  BLK = 256;
constexpr int  UNR = 4;                                   // 16B chunks per thread
constexpr int  CHUNKS = 4000000;                          // 16B chunks per big region (16M elems * 4B / 16B)
constexpr int  GA = (CHUNKS + BLK * UNR - 1) / (BLK * UNR);  // 3907 blocks (indices)
constexpr int  GC = GA;                                      // 3907 blocks (weights)
constexpr int  GB = ((int)NB + BLK - 1) / BLK;               // 513 blocks (offsets)

// clang vector types: accepted by __builtin_nontemporal_load (HIP_vector_type is not).
typedef int   v4i   __attribute__((ext_vector_type(4)));
typedef float v4f   __attribute__((ext_vector_type(4)));
// 16-byte store with only 4-byte alignment: global_store_dwordx4 needs only dword
// alignment, so one instruction covers the out-region misaligned by 1 float.
typedef float v4f_u __attribute__((ext_vector_type(4), aligned(4)));

__global__ __launch_bounds__(BLK) void tbe_prep(
    const int* __restrict__ indices,
    const int* __restrict__ offsets,
    const float* __restrict__ weights,
    float* __restrict__ out) {
  const int bid = blockIdx.x;
  const int tid = threadIdx.x;

  if (bid < GA) {
    // ---- Output 0: indices int32 -> f32 (exact), fully 16B-aligned both sides ----
    const v4i* p = (const v4i*)indices;
    v4f* o = (v4f*)out;
    const int base = bid * (BLK * UNR) + tid;
    v4i a[UNR];
#pragma unroll
    for (int u = 0; u < UNR; ++u) {
      int c = base + u * BLK;
      if (c < CHUNKS) a[u] = __builtin_nontemporal_load(&p[c]);
    }
#pragma unroll
    for (int u = 0; u < UNR; ++u) {
      int c = base + u * BLK;
      if (c < CHUNKS) {
        v4f r;
        r.x = (float)a[u].x; r.y = (float)a[u].y;
        r.z = (float)a[u].z; r.w = (float)a[u].w;
        o[c] = r;
      }
    }
  } else if (bid < GA + GC) {
    // ---- Output 2: weights f32 copy; out region starts at element NA+NB (== 1 mod 4) ----
    const v4f* p = (const v4f*)weights;
    v4f_u* o = (v4f_u*)(out + (NA + NB));   // 4B-aligned 16B stores
    const int base = (bid - GA) * (BLK * UNR) + tid;
    v4f a[UNR];
#pragma unroll
    for (int u = 0; u < UNR; ++u) {
      int c = base + u * BLK;
      if (c < CHUNKS) a[u] = __builtin_nontemporal_load(&p[c]);
    }
#pragma unroll
    for (int u = 0; u < UNR; ++u) {
      int c = base + u * BLK;
      if (c < CHUNKS) o[c] = a[u];
    }
  } else {
    // ---- Output 1: combined_offsets, scalar (131,073 elements, negligible) ----
    long j = (long)(bid - GA - GC) * BLK + tid;
    if (j < NB) {
      int v;
      if (j == NB - 1) {
        v = 16000000;                            // T*L sentinel
      } else {
        int t = (int)(j >> 14);                  // j / B
        int k = (int)(j & 16383);                // j % B
        v = offsets[t * 16385 + k] + t * 2000000;
      }
      out[NA + j] = (float)v;
    }
  }
}

extern "C" void kernel_launch(void* const* d_in, const int* in_sizes, int n_in,
                              void* d_out, int out_size, void* d_ws, size_t ws_size,
                              hipStream_t stream) {
  const int*   indices = (const int*)d_in[0];
  const int*   offsets = (const int*)d_in[1];
  const float* weights = (const float*)d_in[2];
  float*       out     = (float*)d_out;

  const int grid = GA + GC + GB;  // 8,327 blocks
  tbe_prep<<<dim3(grid), dim3(BLK), 0, stream>>>(indices, offsets, weights, out);
}